// Round 10
// baseline (42.740 us; speedup 1.0000x reference)
//
#include <hip/hip_runtime.h>

// SmartCNN round 10: fill-shaped store stream — ONE THREAD PER OUTPUT FLOAT4.
// Wave stores are 1024B fully contiguous, lane-linear, grid walks the output
// array linearly (exactly the fill kernel's pattern, which sustains 6.9 TB/s
// on this box vs our 4.15 TB/s effective with R3's scattered-line quads).
// Each lane: magic-div slot decode, 64B board load (<=3 distinct lines per
// wave, L1 broadcast), u64 nibble pack, 8 LDS gathers, 1 store. Branchless
// zh/zv via fused table + index selects.

__global__ __launch_bounds__(256) void smartcnn_kernel(
    const float* __restrict__ x,
    const float* __restrict__ W0,
    const float* __restrict__ b0,
    const float* __restrict__ W1,
    float* __restrict__ out,
    int B)
{
    // tabs[half*352 + tap*176 + flip*44 + o*11 + e]   (e = log2 class 0..10)
    __shared__ float tabs[704];
    __shared__ float sC[32];     // [half*16 + flip*4 + o] : bias(+h only) + mask contrib

    const int t = threadIdx.x;
    if (t < 176) {
        int flip = t / 44, rem = t % 44, o = rem / 11, e = rem % 11;
        int fvv = flip >> 1, fhh = flip & 1;
        int ch;                              // scrambled channel for class e
        if (e == 0)      ch = fvv ? 0 : 1;   // empty (swaps with mask if fv)
        else if (e == 1) ch = fhh ? 3 : 2;   // class1/class2 swap if fh
        else if (e == 2) ch = fhh ? 2 : 3;
        else             ch = 1 + e;
        tabs[t]       = W0[o * 24 + ch * 2 + 0];
        tabs[176 + t] = W0[o * 24 + ch * 2 + 1];
        tabs[352 + t] = W1[o * 24 + ch * 2 + 0];
        tabs[528 + t] = W1[o * 24 + ch * 2 + 1];
    }
    if (t < 32) {
        int half = t >> 4, flip = (t >> 2) & 3, o = t & 3;
        int mcf = (flip >> 1) & 1;           // mask channel = fv?1:0
        const float* W = half ? W1 : W0;
        float c = W[o * 24 + mcf * 2] + W[o * 24 + mcf * 2 + 1];
        if (!half) c += b0[o];
        sC[t] = c;
    }
    __syncthreads();

    const int f = blockIdx.x * 256 + t;      // global output float4 index
    if (f >= B * 24) return;

    const int b = (int)((unsigned)f / 24u);  // board (compiler magic-div)
    const int slot = f - b * 24;             // 0..11 zh, 12..23 zv^T

    // board load: lanes of a wave touch <=4 consecutive 64B lines
    const float4* x4 = (const float4*)x + (size_t)b * 4;
    float4 r0 = x4[0], r1 = x4[1], r2 = x4[2], r3 = x4[3];

    // corner argmax on the ORIGINAL board (first-max wins)
    float best = r0.x; int ix = 0;
    if (r0.w > best) { best = r0.w; ix = 1; }
    if (r3.x > best) { best = r3.x; ix = 2; }
    if (r3.w > best) { best = r3.w; ix = 3; }
    const int fv = ix >> 1, fh = ix & 1;
    const int M  = fv * 12 + fh * 3;         // flipped-cell -> orig-cell XOR mask
    const int fb = ix * 44;

    // packed nibble classes of the ORIGINAL board -> one u64
#define EVAL(v) (max((int)(__float_as_uint(v) >> 23) - 127, 0))
    unsigned pk0 = (unsigned)EVAL(r0.x)        | ((unsigned)EVAL(r0.y) << 4)  |
                   ((unsigned)EVAL(r0.z) << 8)  | ((unsigned)EVAL(r0.w) << 12) |
                   ((unsigned)EVAL(r1.x) << 16) | ((unsigned)EVAL(r1.y) << 20) |
                   ((unsigned)EVAL(r1.z) << 24) | ((unsigned)EVAL(r1.w) << 28);
    unsigned pk1 = (unsigned)EVAL(r2.x)        | ((unsigned)EVAL(r2.y) << 4)  |
                   ((unsigned)EVAL(r2.z) << 8)  | ((unsigned)EVAL(r2.w) << 12) |
                   ((unsigned)EVAL(r3.x) << 16) | ((unsigned)EVAL(r3.y) << 20) |
                   ((unsigned)EVAL(r3.z) << 24) | ((unsigned)EVAL(r3.w) << 28);
#undef EVAL
    const unsigned long long pk =
        ((unsigned long long)pk1 << 32) | (unsigned long long)pk0;
    // class of FLIPPED cell c: one 64-bit shift (XOR flip folded into shift amt)
#define EX(c) ((int)((pk >> ((((c) ^ M) * 4))) & 15ull))

    // slot decode (once per thread)
    const int half = slot >= 12;             // 0 = zh, 1 = zv^T
    const int n  = half ? slot - 12 : slot;  // float4 index within half
    const int o  = (n * 11) >> 5;            // n/3
    const int s  = n - 3 * o;                // sub-row 0..2
    const int f1 = (s == 2) ? 1 : 0;
    const int f2 = (s >= 1) ? 1 : 0;
    const int s5 = s * 5;

    // first-cell list and partner offset, selected branchlessly by half
    const int c0 = s5;
    const int c1 = half ? s5 + 4 - 11 * f1 : s5 + 1 + f1;
    const int c2 = half ? s5 + 8 - 11 * f2 : s5 + 2 + f2;
    const int c3 = half ? s5 + 1           : s5 + 4;
    const int p  = half ? 4 : 1;

    const int base0 = half * 352 + fb + o * 11;
    const int base1 = base0 + 176;
    const float C = sC[half * 16 + ix * 4 + o];

    float4 val;
    val.x = fmaxf(C + tabs[base0 + EX(c0)] + tabs[base1 + EX(c0 + p)], 0.f);
    val.y = fmaxf(C + tabs[base0 + EX(c1)] + tabs[base1 + EX(c1 + p)], 0.f);
    val.z = fmaxf(C + tabs[base0 + EX(c2)] + tabs[base1 + EX(c2 + p)], 0.f);
    val.w = fmaxf(C + tabs[base0 + EX(c3)] + tabs[base1 + EX(c3 + p)], 0.f);
#undef EX

    ((float4*)out)[f] = val;                 // lane-linear: 1KB contiguous/wave
}

extern "C" void kernel_launch(void* const* d_in, const int* in_sizes, int n_in,
                              void* d_out, int out_size, void* d_ws, size_t ws_size,
                              hipStream_t stream) {
    const float* x  = (const float*)d_in[0];
    const float* W0 = (const float*)d_in[1];
    const float* b0 = (const float*)d_in[2];
    const float* W1 = (const float*)d_in[3];
    float* out = (float*)d_out;

    int B = in_sizes[0] / 16;                // boards
    int total = B * 24;                      // output float4 count
    int blocks = (total + 255) / 256;
    smartcnn_kernel<<<blocks, 256, 0, stream>>>(x, W0, b0, W1, out, B);
}

// Round 11
// 25.015 us; speedup vs baseline: 1.7086x; 1.7086x over previous
//
#include <hip/hip_runtime.h>

// SmartCNN round 11: R3 kernel body, but 2048 blocks x 256 threads, one-shot
// full residency (8 blocks/CU = 32 waves/CU), each thread runs exactly TWO
// board-quads (gq and gq+half, same q), fully unrolled. Dispatch ramp /8,
// table-init /8, residency unchanged vs R3. Single-variable test of the
// ramp/init-amortization hypothesis (R5/R8 were confounded: they also cut
// resident waves or added loop overhead).

#define PROCESS(GQ)                                                            \
    do {                                                                       \
        const int gq_ = (GQ);                                                  \
        if (gq_ < nq) {                                                        \
            const int b = gq_ >> 2;                                            \
            const int q = gq_ & 3;                                             \
            const float4* x4 = (const float4*)x + (size_t)b * 4;               \
            float4 r0 = x4[0], r1 = x4[1], r2 = x4[2], r3 = x4[3];             \
            float best = r0.x; int ix = 0;                                     \
            if (r0.w > best) { best = r0.w; ix = 1; }                          \
            if (r3.x > best) { best = r3.x; ix = 2; }                          \
            if (r3.w > best) { best = r3.w; ix = 3; }                          \
            const int flipsel = ix;                                            \
            const int fv = ix >> 1, fh = ix & 1;                               \
            const int M  = fv * 12 + fh * 3;                                   \
            const int fb = flipsel * 44;                                       \
            unsigned pack0 = (unsigned)EVAL(r0.x)        | ((unsigned)EVAL(r0.y) << 4)  | \
                             ((unsigned)EVAL(r0.z) << 8)  | ((unsigned)EVAL(r0.w) << 12) | \
                             ((unsigned)EVAL(r1.x) << 16) | ((unsigned)EVAL(r1.y) << 20) | \
                             ((unsigned)EVAL(r1.z) << 24) | ((unsigned)EVAL(r1.w) << 28); \
            unsigned pack1 = (unsigned)EVAL(r2.x)        | ((unsigned)EVAL(r2.y) << 4)  | \
                             ((unsigned)EVAL(r2.z) << 8)  | ((unsigned)EVAL(r2.w) << 12) | \
                             ((unsigned)EVAL(r3.x) << 16) | ((unsigned)EVAL(r3.y) << 20) | \
                             ((unsigned)EVAL(r3.z) << 24) | ((unsigned)EVAL(r3.w) << 28); \
            float4* out4 = (float4*)out + (size_t)b * 24;                      \
            _Pragma("unroll")                                                  \
            for (int rp = 0; rp < 3; ++rp) {                                   \
                const int n  = rp * 4 + q;                                     \
                const int o  = (n * 11) >> 5;                                  \
                const int s  = n - 3 * o;                                      \
                const int f1 = (s == 2) ? 1 : 0;                               \
                const int f2 = (s >= 1) ? 1 : 0;                               \
                const int s5 = s * 5;                                          \
                const int base = fb + o * 11;                                  \
                {                                                              \
                    const float Ch = sC0[flipsel * 4 + o];                     \
                    int c0 = s5, c1 = s5 + 1 + f1, c2 = s5 + 2 + f2, c3 = s5 + 4; \
                    float4 val;                                                \
                    val.x = fmaxf(Ch + tab0h[base + EX(c0 ^ M)] + tab1h[base + EX((c0 + 1) ^ M)], 0.f); \
                    val.y = fmaxf(Ch + tab0h[base + EX(c1 ^ M)] + tab1h[base + EX((c1 + 1) ^ M)], 0.f); \
                    val.z = fmaxf(Ch + tab0h[base + EX(c2 ^ M)] + tab1h[base + EX((c2 + 1) ^ M)], 0.f); \
                    val.w = fmaxf(Ch + tab0h[base + EX(c3 ^ M)] + tab1h[base + EX((c3 + 1) ^ M)], 0.f); \
                    out4[rp * 4 + q] = val;                                    \
                }                                                              \
                {                                                              \
                    const float Cv = sC1[flipsel * 4 + o];                     \
                    int c0 = s5, c1 = s5 + 4 - 11 * f1, c2 = s5 + 8 - 11 * f2, c3 = s5 + 1; \
                    float4 val;                                                \
                    val.x = fmaxf(Cv + tab0v[base + EX(c0 ^ M)] + tab1v[base + EX((c0 + 4) ^ M)], 0.f); \
                    val.y = fmaxf(Cv + tab0v[base + EX(c1 ^ M)] + tab1v[base + EX((c1 + 4) ^ M)], 0.f); \
                    val.z = fmaxf(Cv + tab0v[base + EX(c2 ^ M)] + tab1v[base + EX((c2 + 4) ^ M)], 0.f); \
                    val.w = fmaxf(Cv + tab0v[base + EX(c3 ^ M)] + tab1v[base + EX((c3 + 4) ^ M)], 0.f); \
                    out4[12 + rp * 4 + q] = val;                               \
                }                                                              \
            }                                                                  \
        }                                                                      \
    } while (0)

#define EVAL(v) (max((int)(__float_as_uint(v) >> 23) - 127, 0))
#define EX(c) (int)((((c) & 8) ? pack1 : pack0) >> (((c) & 7) * 4) & 15u)

__global__ __launch_bounds__(256, 8) void smartcnn_kernel(
    const float* __restrict__ x,
    const float* __restrict__ W0,
    const float* __restrict__ b0,
    const float* __restrict__ W1,
    float* __restrict__ out,
    int B, int half)
{
    // flip-specialized tables: idx = flip*44 + o*11 + e   (e = log2 class 0..10)
    __shared__ float tab0h[176], tab1h[176];  // W0 tap0 / tap1 (horizontal conv)
    __shared__ float tab0v[176], tab1v[176];  // W1 tap0 / tap1 (vertical conv)
    __shared__ float sC0[16], sC1[16];        // per (flip,o): bias + mask contrib

    const int t = threadIdx.x;
    if (t < 176) {
        int flip = t / 44, rem = t % 44, o = rem / 11, e = rem % 11;
        int fvv = flip >> 1, fhh = flip & 1;
        int ch;                              // scrambled channel for class e
        if (e == 0)      ch = fvv ? 0 : 1;   // empty (swaps with mask if fv)
        else if (e == 1) ch = fhh ? 3 : 2;   // class1/class2 swap if fh
        else if (e == 2) ch = fhh ? 2 : 3;
        else             ch = 1 + e;
        tab0h[t] = W0[o * 24 + ch * 2 + 0];
        tab1h[t] = W0[o * 24 + ch * 2 + 1];
        tab0v[t] = W1[o * 24 + ch * 2 + 0];
        tab1v[t] = W1[o * 24 + ch * 2 + 1];
    }
    if (t < 16) {
        int flip = t >> 2, o = t & 3, mcf = (flip >> 1) & 1;  // mask ch = fv?1:0
        sC0[t] = b0[o] + W0[o * 24 + mcf * 2] + W0[o * 24 + mcf * 2 + 1];
        sC1[t] =          W1[o * 24 + mcf * 2] + W1[o * 24 + mcf * 2 + 1];
    }
    __syncthreads();

    const int nq = B * 4;
    const int tid = blockIdx.x * 256 + t;

    PROCESS(tid);
    PROCESS(tid + half);
}

#undef EX
#undef EVAL
#undef PROCESS

extern "C" void kernel_launch(void* const* d_in, const int* in_sizes, int n_in,
                              void* d_out, int out_size, void* d_ws, size_t ws_size,
                              hipStream_t stream) {
    const float* x  = (const float*)d_in[0];
    const float* W0 = (const float*)d_in[1];
    const float* b0 = (const float*)d_in[2];
    const float* W1 = (const float*)d_in[3];
    float* out = (float*)d_out;

    int B = in_sizes[0] / 16;                 // boards
    int nq = B * 4;                           // quads (4 lanes per board)
    int half = (nq + 1) >> 1;                 // 2 tasks per thread
    int blocks = (half + 255) / 256;          // B=262144 -> 2048 blocks
    smartcnn_kernel<<<blocks, 256, 0, stream>>>(x, W0, b0, W1, out, B, half);
}

// Round 12
// 24.338 us; speedup vs baseline: 1.7561x; 1.0278x over previous
//
#include <hip/hip_runtime.h>

// SmartCNN FINAL (= round-9 best, 24.25 us): quad-per-board, flip-specialized
// LDS weight tables, packed-nibble board classes, transaction-minimal stores.
//
// Probe history (all vs this structure's 24.3 us):
//   R4  LDS-gathers/2 + VALU/2        -> neutral   (not LDS/VALU-bound)
//   R5  persistent grid-stride        -> -4 us
//   R7  nontemporal stores            -> -7 us     (L2 aggregation helps)
//   R8  4-task unroll, low residency  -> -2 us
//   R9  __launch_bounds__(256,8)      -> neutral   (not occupancy-bound)
//   R10 lane-linear contiguous stores -> -18 us    (input read amplification)
//   R11 ramp/8 + init/8, full resid.  -> neutral
// => 4.84 TB/s on an 86%-write 117.5 MB mixed stream is the converged
//    memory-system ceiling for this op (fill=6.9, copy=6.3 TB/s bounds).
//
// Mapping: lane quad q=0..3 of board b writes float4s m = 4r+q (r=0..5) at
// out4[b*24+m] -> every store instr = 16 full 64B lines. Flip scramble is
// folded into 4 flip-specialized weight tables in LDS; spatial flip into a
// cell-index XOR (fv:^12, fh:^3); per-cell classes into two packed nibble
// u32s (runtime cell index = bit-extract, never a register-array index).

__global__ __launch_bounds__(256, 8) void smartcnn_kernel(
    const float* __restrict__ x,
    const float* __restrict__ W0,
    const float* __restrict__ b0,
    const float* __restrict__ W1,
    float* __restrict__ out,
    int B)
{
    // flip-specialized tables: idx = flip*44 + o*11 + e   (e = log2 class 0..10)
    __shared__ float tab0h[176], tab1h[176];  // W0 tap0 / tap1 (horizontal conv)
    __shared__ float tab0v[176], tab1v[176];  // W1 tap0 / tap1 (vertical conv)
    __shared__ float sC0[16], sC1[16];        // per (flip,o): bias + mask contribution

    const int t = threadIdx.x;
    if (t < 176) {
        int flip = t / 44, rem = t % 44, o = rem / 11, e = rem % 11;
        int fvv = flip >> 1, fhh = flip & 1;
        int ch;                              // scrambled channel for class e
        if (e == 0)      ch = fvv ? 0 : 1;   // empty (swaps with mask if fv)
        else if (e == 1) ch = fhh ? 3 : 2;   // class1/class2 swap if fh
        else if (e == 2) ch = fhh ? 2 : 3;
        else             ch = 1 + e;
        tab0h[t] = W0[o * 24 + ch * 2 + 0];
        tab1h[t] = W0[o * 24 + ch * 2 + 1];
        tab0v[t] = W1[o * 24 + ch * 2 + 0];
        tab1v[t] = W1[o * 24 + ch * 2 + 1];
    }
    if (t < 16) {
        int flip = t >> 2, o = t & 3, mcf = (flip >> 1) & 1;  // mask channel = fv?1:0
        sC0[t] = b0[o] + W0[o * 24 + mcf * 2] + W0[o * 24 + mcf * 2 + 1];
        sC1[t] =          W1[o * 24 + mcf * 2] + W1[o * 24 + mcf * 2 + 1];
    }
    __syncthreads();

    int gq = blockIdx.x * 256 + t;
    int b = gq >> 2;        // board
    int q = gq & 3;         // which float4 of each 64B output line
    if (b >= B) return;

    // load full board (quad lanes hit the same line; L1 serves the re-reads)
    const float4* x4 = (const float4*)x + (size_t)b * 4;
    float4 r0 = x4[0], r1 = x4[1], r2 = x4[2], r3 = x4[3];

    // corner argmax on the ORIGINAL board (first-max wins)
    float best = r0.x; int ix = 0;
    if (r0.w > best) { best = r0.w; ix = 1; }
    if (r3.x > best) { best = r3.x; ix = 2; }
    if (r3.w > best) { best = r3.w; ix = 3; }
    const int flipsel = ix;                 // fv*2 + fh
    const int fv = ix >> 1, fh = ix & 1;
    const int M  = fv * 12 + fh * 3;        // flipped-cell -> orig-cell XOR mask
    const int fb = flipsel * 44;            // table base (entries)

    // packed nibble classes of the ORIGINAL board, cell = row*4+col
#define EVAL(v) (max((int)(__float_as_uint(v) >> 23) - 127, 0))
    unsigned pack0 = (unsigned)EVAL(r0.x)        | ((unsigned)EVAL(r0.y) << 4)  |
                     ((unsigned)EVAL(r0.z) << 8)  | ((unsigned)EVAL(r0.w) << 12) |
                     ((unsigned)EVAL(r1.x) << 16) | ((unsigned)EVAL(r1.y) << 20) |
                     ((unsigned)EVAL(r1.z) << 24) | ((unsigned)EVAL(r1.w) << 28);
    unsigned pack1 = (unsigned)EVAL(r2.x)        | ((unsigned)EVAL(r2.y) << 4)  |
                     ((unsigned)EVAL(r2.z) << 8)  | ((unsigned)EVAL(r2.w) << 12) |
                     ((unsigned)EVAL(r3.x) << 16) | ((unsigned)EVAL(r3.y) << 20) |
                     ((unsigned)EVAL(r3.z) << 24) | ((unsigned)EVAL(r3.w) << 28);
#undef EVAL

    // class of orig cell c (0..15)
#define EX(c) (int)(((c) < 8 ? pack0 : pack1) >> (((c) & 7) * 4) & 15u)

    float4* out4 = (float4*)out + (size_t)b * 24;

#pragma unroll
    for (int rp = 0; rp < 3; ++rp) {        // rp = r%3 ; handles zh (r=rp) and zv (r=rp+3)
        const int n  = rp * 4 + q;          // f4 index within 48-float half
        const int o  = (n * 11) >> 5;       // n/3 for n<12
        const int s  = n - 3 * o;           // sub-row 0..2
        const int f1 = (s == 2) ? 1 : 0;
        const int f2 = (s >= 1) ? 1 : 0;
        const int s5 = s * 5;
        const int base = fb + o * 11;

        // ---- zh: cells (i,j),(i,j+1) in flipped space; cf = 5s+c+carry ----
        {
            const float Ch = sC0[flipsel * 4 + o];
            int c0 = s5, c1 = s5 + 1 + f1, c2 = s5 + 2 + f2, c3 = s5 + 4;
            float4 val;
            val.x = fmaxf(Ch + tab0h[base + EX(c0 ^ M)] + tab1h[base + EX((c0 + 1) ^ M)], 0.f);
            val.y = fmaxf(Ch + tab0h[base + EX(c1 ^ M)] + tab1h[base + EX((c1 + 1) ^ M)], 0.f);
            val.z = fmaxf(Ch + tab0h[base + EX(c2 ^ M)] + tab1h[base + EX((c2 + 1) ^ M)], 0.f);
            val.w = fmaxf(Ch + tab0h[base + EX(c3 ^ M)] + tab1h[base + EX((c3 + 1) ^ M)], 0.f);
            out4[rp * 4 + q] = val;
        }
        // ---- zv^T: cells (qq,a),(qq+1,a); cf = 5s+4c-11*carry ----
        {
            const float Cv = sC1[flipsel * 4 + o];
            int c0 = s5, c1 = s5 + 4 - 11 * f1, c2 = s5 + 8 - 11 * f2, c3 = s5 + 1;
            float4 val;
            val.x = fmaxf(Cv + tab0v[base + EX(c0 ^ M)] + tab1v[base + EX((c0 + 4) ^ M)], 0.f);
            val.y = fmaxf(Cv + tab0v[base + EX(c1 ^ M)] + tab1v[base + EX((c1 + 4) ^ M)], 0.f);
            val.z = fmaxf(Cv + tab0v[base + EX(c2 ^ M)] + tab1v[base + EX((c2 + 4) ^ M)], 0.f);
            val.w = fmaxf(Cv + tab0v[base + EX(c3 ^ M)] + tab1v[base + EX((c3 + 4) ^ M)], 0.f);
            out4[12 + rp * 4 + q] = val;
        }
    }
#undef EX
}

extern "C" void kernel_launch(void* const* d_in, const int* in_sizes, int n_in,
                              void* d_out, int out_size, void* d_ws, size_t ws_size,
                              hipStream_t stream) {
    const float* x  = (const float*)d_in[0];
    const float* W0 = (const float*)d_in[1];
    const float* b0 = (const float*)d_in[2];
    const float* W1 = (const float*)d_in[3];
    float* out = (float*)d_out;

    int B = in_sizes[0] / 16;                 // boards
    int total = B * 4;                        // 4 lanes per board
    int blocks = (total + 255) / 256;
    smartcnn_kernel<<<blocks, 256, 0, stream>>>(x, W0, b0, W1, out, B);
}